// Round 5
// baseline (499.248 us; speedup 1.0000x reference)
//
#include <hip/hip_runtime.h>

using u16 = unsigned short;
using u32 = unsigned int;

typedef __attribute__((ext_vector_type(8))) short bf16x8;   // 8 bf16 (4 VGPRs) MFMA frag
typedef __attribute__((ext_vector_type(4))) float f32x4;
typedef __attribute__((ext_vector_type(8))) u16 u16x8;
typedef __attribute__((ext_vector_type(4))) u16 u16x4;

constexpr int NB = 64, NC = 729, NS = 243, ND = 512, ND2 = 1024;
constexpr int MS = NB * NS;   // 15552 set rows
constexpr int MC = NB * NC;   // 46656 cand rows
constexpr int MCH = MC / 3;   // 15552 rows per FF2 chunk

__device__ __forceinline__ u16 f2bf(float f) {
  u32 u = __builtin_bit_cast(u32, f);
  return (u16)((u + 0x7fffu + ((u >> 16) & 1u)) >> 16);   // RNE
}
__device__ __forceinline__ float bf2f(u16 h) {
  return __builtin_bit_cast(float, (u32)h << 16);
}
__device__ __forceinline__ void gload16(const void* g, void* l) {
  __builtin_amdgcn_global_load_lds((const __attribute__((address_space(1))) u32*)g,
                                   (__attribute__((address_space(3))) u32*)l, 16, 0, 0);
}

// ---------------- weight f32 -> bf16 cast ----------------
__global__ __launch_bounds__(256) void cast_bf16_k(const float* __restrict__ in,
                                                   u16* __restrict__ out, int n4) {
  int i = blockIdx.x * 256 + threadIdx.x;
  if (i >= n4) return;
  f32x4 v = ((const f32x4*)in)[i];
  u16x4 o;
  o.x = f2bf(v.x); o.y = f2bf(v.y); o.z = f2bf(v.z); o.w = f2bf(v.w);
  ((u16x4*)out)[i] = o;
}

// ---------------- CSR build (deterministic, parallel rank-in-prefix) ----------------
// list order within each set == entry order (same as old serial fill -> identical
// fp32 accumulation order downstream).
__global__ __launch_bounds__(1024) void build_csr_k(const int* __restrict__ idx,
                                                    int* __restrict__ offs,
                                                    int* __restrict__ list) {
  __shared__ int sidx[3 * NC];    // 2187 entries
  __shared__ int cnts[NS];
  __shared__ int soffs[NS + 1];
  const int t = threadIdx.x;
  for (int e = t; e < 3 * NC; e += 1024) sidx[e] = idx[e];
  for (int s = t; s < NS; s += 1024) cnts[s] = 0;
  __syncthreads();
  for (int e = t; e < 3 * NC; e += 1024) atomicAdd(&cnts[sidx[e]], 1);
  __syncthreads();
  if (t == 0) {
    int a = 0;
    for (int s = 0; s < NS; ++s) { soffs[s] = a; a += cnts[s]; }
    soffs[NS] = a;
  }
  __syncthreads();
  for (int s = t; s <= NS; s += 1024) offs[s] = soffs[s];
  for (int e = t; e < 3 * NC; e += 1024) {
    int s = sidx[e], r = 0;
    for (int e2 = 0; e2 < e; ++e2) r += (sidx[e2] == s) ? 1 : 0;
    list[soffs[s] + r] = e / 3;    // candidate index (repeat(3) => c = e/3)
  }
}

// ---------------- per-set aggregation of cand_feat (pre-GEMM1 scatter) ----------------
__global__ __launch_bounds__(256) void agg_k(const float* __restrict__ cand_feat,
                                             const int* __restrict__ offs,
                                             const int* __restrict__ list,
                                             u16* __restrict__ agg) {
  int row = blockIdx.x * 4 + (threadIdx.x >> 6);
  if (row >= MS) return;
  int lane = threadIdx.x & 63;
  int b = row / NS, s = row - b * NS;
  int e0 = offs[s], e1 = offs[s + 1];
  const float* base = cand_feat + (size_t)b * NC * ND + lane * 8;
  f32x4 a0 = {0.f, 0.f, 0.f, 0.f}, a1 = {0.f, 0.f, 0.f, 0.f};
  for (int e = e0; e < e1; ++e) {
    const float* p = base + (size_t)list[e] * ND;
    a0 += *(const f32x4*)p;
    a1 += *(const f32x4*)(p + 4);
  }
  u16x8 o;
  o[0] = f2bf(a0.x); o[1] = f2bf(a0.y); o[2] = f2bf(a0.z); o[3] = f2bf(a0.w);
  o[4] = f2bf(a1.x); o[5] = f2bf(a1.y); o[6] = f2bf(a1.z); o[7] = f2bf(a1.w);
  *(u16x8*)(agg + (size_t)row * ND + lane * 8) = o;
}

// ============ m97-structure 128x128 bf16 GEMM, C = A @ B^T ============
// BK=32, single-buffer 16KB LDS, 256 threads, 3 blocks/CU (inter-block overlap
// hides barrier drains — m97/m114). Coalesced 64B-row staging with
// s(row)=(row^(row>>2))&3 chunk swizzle (pre-swizzled global source, linear
// LDS dest) -> conflict-free ds_read_b128.
// EP=0: f32, no bias.  EP=1: bias+relu -> bf16.  EP=2: bias -> bf16.
template <int EP>
__global__ __launch_bounds__(256, 3) void gemm_m97_k(const u16* __restrict__ A,
                                                     const u16* __restrict__ Bw,
                                                     void* __restrict__ Out,
                                                     const float* __restrict__ bias,
                                                     int M, int N, int K) {
  constexpr int BK = 32;
  __shared__ u16 lA[128 * BK];   // 8 KB, [row][4 chunks of 8 elems]
  __shared__ u16 lB[128 * BK];   // 8 KB
  const int t = threadIdx.x, wid = t >> 6, lane = t & 63;
  const int MT = (M + 127) >> 7;
  const int mt = blockIdx.x % MT, nt = blockIdx.x / MT;
  const int m0 = mt << 7, n0 = nt << 7;

  const int srow = t >> 2, sc = t & 3;                       // srow 0..63
  const int cp = (sc ^ ((srow ^ (srow >> 2)) & 3)) * 8;      // swizzled src chunk
  int ra0 = m0 + srow;       if (ra0 > M - 1) ra0 = M - 1;   // tail clamp (A only)
  int ra1 = m0 + 64 + srow;  if (ra1 > M - 1) ra1 = M - 1;
  const u16* gA0 = A + (size_t)ra0 * K + cp;
  const u16* gA1 = A + (size_t)ra1 * K + cp;
  const u16* gB0 = Bw + (size_t)(n0 + srow) * K + cp;
  const u16* gB1 = Bw + (size_t)(n0 + 64 + srow) * K + cp;

  const int li = lane & 15, g0 = lane >> 4;
  const int sw = (li ^ (li >> 2)) & 3;
  const int wr = wid >> 1, wc = wid & 1;
  const int aBase = (wr * 64 + li) * BK + ((g0 ^ sw) << 3);
  const int bBase = (wc * 64 + li) * BK + ((g0 ^ sw) << 3);

  f32x4 acc[4][4] = {};

  for (int kt = 0; kt < K; kt += BK) {
    gload16(gA0, lA + t * 8); gload16(gA1, lA + t * 8 + 2048);
    gload16(gB0, lB + t * 8); gload16(gB1, lB + t * 8 + 2048);
    gA0 += BK; gA1 += BK; gB0 += BK; gB1 += BK;
    __syncthreads();
    bf16x8 af[4], bfr[4];
#pragma unroll
    for (int i = 0; i < 4; ++i) {
      af[i]  = *(const bf16x8*)(lA + aBase + i * 512);
      bfr[i] = *(const bf16x8*)(lB + bBase + i * 512);
    }
#pragma unroll
    for (int mi = 0; mi < 4; ++mi)
#pragma unroll
      for (int ni = 0; ni < 4; ++ni)
        acc[mi][ni] = __builtin_amdgcn_mfma_f32_16x16x32_bf16(af[mi], bfr[ni], acc[mi][ni], 0, 0, 0);
    __syncthreads();
  }

  const int rb = m0 + wr * 64 + (g0 << 2);
  const int cb = n0 + wc * 64 + li;
  if (EP == 0) {
    float* O = (float*)Out;
#pragma unroll
    for (int mi = 0; mi < 4; ++mi)
#pragma unroll
      for (int ni = 0; ni < 4; ++ni) {
        int cc = cb + ni * 16;
#pragma unroll
        for (int r = 0; r < 4; ++r) {
          int rr = rb + mi * 16 + r;
          if (rr < M) O[(size_t)rr * N + cc] = acc[mi][ni][r];
        }
      }
  } else {
    u16* O = (u16*)Out;
    float bv[4];
#pragma unroll
    for (int ni = 0; ni < 4; ++ni) bv[ni] = bias[cb + ni * 16];
#pragma unroll
    for (int mi = 0; mi < 4; ++mi)
#pragma unroll
      for (int ni = 0; ni < 4; ++ni) {
        int cc = cb + ni * 16;
#pragma unroll
        for (int r = 0; r < 4; ++r) {
          int rr = rb + mi * 16 + r;
          float v = acc[mi][ni][r] + bv[ni];
          if (EP == 1) v = fmaxf(v, 0.0f);
          if (rr < M) O[(size_t)rr * N + cc] = f2bf(v);
        }
      }
  }
}

// ---------------- set LN: set_out = LN(set_feat + (u1 + cnt*b_vc)/9) ----------------
__global__ __launch_bounds__(256) void set_ln_k(const float* __restrict__ u1,
                                                const float* __restrict__ set_feat,
                                                const int* __restrict__ offs,
                                                const float* __restrict__ b_vc,
                                                const float* __restrict__ gam,
                                                const float* __restrict__ bet,
                                                float* __restrict__ set_out,
                                                u16* __restrict__ set_out_bf) {
  int row = blockIdx.x * 4 + (threadIdx.x >> 6);
  if (row >= MS) return;
  int lane = threadIdx.x & 63;
  int s = row % NS;
  float c9 = (float)(offs[s + 1] - offs[s]) * (1.0f / 9.0f);
  size_t base = (size_t)row * ND + lane * 8;
  f32x4 u0 = *(const f32x4*)(u1 + base),       u1b = *(const f32x4*)(u1 + base + 4);
  f32x4 s0 = *(const f32x4*)(set_feat + base), s1  = *(const f32x4*)(set_feat + base + 4);
  f32x4 b0 = *(const f32x4*)(b_vc + lane * 8), b1  = *(const f32x4*)(b_vc + lane * 8 + 4);
  f32x4 x0 = s0 + u0 * (1.0f / 9.0f) + b0 * c9;
  f32x4 x1 = s1 + u1b * (1.0f / 9.0f) + b1 * c9;
  float sm = 0.f, sq = 0.f;
#pragma unroll
  for (int i = 0; i < 4; ++i) { sm += x0[i] + x1[i]; sq += x0[i] * x0[i] + x1[i] * x1[i]; }
#pragma unroll
  for (int m = 32; m; m >>= 1) { sm += __shfl_xor(sm, m); sq += __shfl_xor(sq, m); }
  float mu = sm * (1.0f / ND);
  float rs = rsqrtf(sq * (1.0f / ND) - mu * mu + 1e-5f);
  f32x4 g0 = *(const f32x4*)(gam + lane * 8), g1 = *(const f32x4*)(gam + lane * 8 + 4);
  f32x4 e0 = *(const f32x4*)(bet + lane * 8), e1 = *(const f32x4*)(bet + lane * 8 + 4);
  f32x4 y0, y1; u16x8 ob;
#pragma unroll
  for (int i = 0; i < 4; ++i) {
    y0[i] = (x0[i] - mu) * rs * g0[i] + e0[i];
    y1[i] = (x1[i] - mu) * rs * g1[i] + e1[i];
    ob[i] = f2bf(y0[i]); ob[i + 4] = f2bf(y1[i]);
  }
  *(f32x4*)(set_out + base) = y0;
  *(f32x4*)(set_out + base + 4) = y1;
  *(u16x8*)(set_out_bf + base) = ob;
}

// ---------------- cand LN: cand_h = LN(cand_feat + mean3(proj) + b_vs) ----------------
__global__ __launch_bounds__(256) void cand_ln_k(const float* __restrict__ cand_feat,
                                                 const float* __restrict__ proj,
                                                 const int* __restrict__ cidx,
                                                 const float* __restrict__ b_vs,
                                                 const float* __restrict__ gam,
                                                 const float* __restrict__ bet,
                                                 u16* __restrict__ cand_h) {
  int row = blockIdx.x * 4 + (threadIdx.x >> 6);
  if (row >= MC) return;
  int lane = threadIdx.x & 63;
  int b = row / NC, c = row - b * NC;
  int i0 = cidx[c * 3], i1 = cidx[c * 3 + 1], i2 = cidx[c * 3 + 2];
  const float* pb = proj + (size_t)b * NS * ND + lane * 8;
  f32x4 p00 = *(const f32x4*)(pb + (size_t)i0 * ND), p01 = *(const f32x4*)(pb + (size_t)i0 * ND + 4);
  f32x4 p10 = *(const f32x4*)(pb + (size_t)i1 * ND), p11 = *(const f32x4*)(pb + (size_t)i1 * ND + 4);
  f32x4 p20 = *(const f32x4*)(pb + (size_t)i2 * ND), p21 = *(const f32x4*)(pb + (size_t)i2 * ND + 4);
  size_t base = (size_t)row * ND + lane * 8;
  f32x4 c0 = *(const f32x4*)(cand_feat + base), c1 = *(const f32x4*)(cand_feat + base + 4);
  f32x4 v0 = *(const f32x4*)(b_vs + lane * 8),  v1 = *(const f32x4*)(b_vs + lane * 8 + 4);
  const float third = 1.0f / 3.0f;
  f32x4 x0 = c0 + (p00 + p10 + p20) * third + v0;
  f32x4 x1 = c1 + (p01 + p11 + p21) * third + v1;
  float sm = 0.f, sq = 0.f;
#pragma unroll
  for (int i = 0; i < 4; ++i) { sm += x0[i] + x1[i]; sq += x0[i] * x0[i] + x1[i] * x1[i]; }
#pragma unroll
  for (int m = 32; m; m >>= 1) { sm += __shfl_xor(sm, m); sq += __shfl_xor(sq, m); }
  float mu = sm * (1.0f / ND);
  float rs = rsqrtf(sq * (1.0f / ND) - mu * mu + 1e-5f);
  f32x4 g0 = *(const f32x4*)(gam + lane * 8), g1 = *(const f32x4*)(gam + lane * 8 + 4);
  f32x4 e0 = *(const f32x4*)(bet + lane * 8), e1 = *(const f32x4*)(bet + lane * 8 + 4);
  u16x8 ob;
#pragma unroll
  for (int i = 0; i < 4; ++i) {
    ob[i]     = f2bf((x0[i] - mu) * rs * g0[i] + e0[i]);
    ob[i + 4] = f2bf((x1[i] - mu) * rs * g1[i] + e1[i]);
  }
  *(u16x8*)(cand_h + base) = ob;
}

// ---------------- final LN: out = LN(cand_h + h2b) (bias folded into h2b) ----------------
__global__ __launch_bounds__(256) void ln_ff_k(const u16* __restrict__ h2b,
                                               const u16* __restrict__ resid,
                                               const float* __restrict__ gam,
                                               const float* __restrict__ bet,
                                               float* __restrict__ out, int nrows) {
  int row = blockIdx.x * 4 + (threadIdx.x >> 6);
  if (row >= nrows) return;
  int lane = threadIdx.x & 63;
  size_t base = (size_t)row * ND + lane * 8;
  u16x8 ha = *(const u16x8*)(h2b + base);
  u16x8 ra = *(const u16x8*)(resid + base);
  float x[8];
  float sm = 0.f, sq = 0.f;
#pragma unroll
  for (int i = 0; i < 8; ++i) {
    x[i] = bf2f(ha[i]) + bf2f(ra[i]);
    sm += x[i]; sq += x[i] * x[i];
  }
#pragma unroll
  for (int m = 32; m; m >>= 1) { sm += __shfl_xor(sm, m); sq += __shfl_xor(sq, m); }
  float mu = sm * (1.0f / ND);
  float rs = rsqrtf(sq * (1.0f / ND) - mu * mu + 1e-5f);
  f32x4 g0 = *(const f32x4*)(gam + lane * 8), g1 = *(const f32x4*)(gam + lane * 8 + 4);
  f32x4 e0 = *(const f32x4*)(bet + lane * 8), e1 = *(const f32x4*)(bet + lane * 8 + 4);
  f32x4 y0, y1;
#pragma unroll
  for (int i = 0; i < 4; ++i) {
    y0[i] = (x[i] - mu) * rs * g0[i] + e0[i];
    y1[i] = (x[i + 4] - mu) * rs * g1[i] + e1[i];
  }
  *(f32x4*)(out + base) = y0;
  *(f32x4*)(out + base + 4) = y1;
}

// ---------------- launcher ----------------
extern "C" void kernel_launch(void* const* d_in, const int* in_sizes, int n_in,
                              void* d_out, int out_size, void* d_ws, size_t ws_size,
                              hipStream_t stream) {
  const float* cand_feat = (const float*)d_in[0];
  const float* set_feat  = (const float*)d_in[1];
  const float* W_vc  = (const float*)d_in[2];
  const float* b_vc  = (const float*)d_in[3];
  const float* W_vs  = (const float*)d_in[4];
  const float* b_vs  = (const float*)d_in[5];
  const float* ff_W1 = (const float*)d_in[6];
  const float* ff_b1 = (const float*)d_in[7];
  const float* ff_W2 = (const float*)d_in[8];
  const float* ff_b2 = (const float*)d_in[9];
  const float* g_set  = (const float*)d_in[10];
  const float* be_set = (const float*)d_in[11];
  const float* g_cand = (const float*)d_in[12];
  const float* be_cand= (const float*)d_in[13];
  const float* g_ff   = (const float*)d_in[14];
  const float* be_ff  = (const float*)d_in[15];
  const int*   cidx   = (const int*)d_in[16];
  (void)in_sizes; (void)n_in; (void)out_size; (void)ws_size;

  // workspace layout (max used: 20MB + 47.8MB ~= 68MB, proven by R1-R3 passes)
  char* ws = (char*)d_ws;
  u16* w_vc_b = (u16*)(ws + 0);
  u16* w_vs_b = (u16*)(ws + (512 << 10));
  u16* w1_b   = (u16*)(ws + (1 << 20));
  u16* w2_b   = (u16*)(ws + (2 << 20));
  int* offs   = (int*)(ws + (3 << 20));
  int* list   = (int*)(ws + (3 << 20) + 4096);
  u16* setb   = (u16*)(ws + (4 << 20));        // 15.9 MB  set_out bf16; later FF2 h2 chunk
  u16* candh  = (u16*)(ws + (20 << 20));       // 47.8 MB  cand_h bf16 (ends ~67.8MB)
  u16* h2chunk = setb;                         // reuse: setb dead after GEMM2

  // d_out region reuse (cand region = 95.55 MB, written last):
  float* out_cand = (float*)d_out;
  float* out_set  = out_cand + (size_t)MC * ND;
  u16*   agg  = (u16*)out_set;     // 15.9 MB, dead before set_out written
  float* u1   = out_cand;          // GEMM1 out, dead after set_ln
  float* proj = out_cand;          // GEMM2 out, dead after cand_ln
  u16*   h1   = (u16*)out_cand;    // FF1 out (46656 x 1024 bf16 = exactly the cand region)

  cast_bf16_k<<<(ND * ND / 4 + 255) / 256, 256, 0, stream>>>(W_vc, w_vc_b, ND * ND / 4);
  cast_bf16_k<<<(ND * ND / 4 + 255) / 256, 256, 0, stream>>>(W_vs, w_vs_b, ND * ND / 4);
  cast_bf16_k<<<(ND2 * ND / 4 + 255) / 256, 256, 0, stream>>>(ff_W1, w1_b, ND2 * ND / 4);
  cast_bf16_k<<<(ND * ND2 / 4 + 255) / 256, 256, 0, stream>>>(ff_W2, w2_b, ND * ND2 / 4);
  build_csr_k<<<1, 1024, 0, stream>>>(cidx, offs, list);
  agg_k<<<(MS + 3) / 4, 256, 0, stream>>>(cand_feat, offs, list, agg);
  gemm_m97_k<0><<<122 * 4, 256, 0, stream>>>(agg, w_vc_b, u1, nullptr, MS, ND, ND);
  set_ln_k<<<(MS + 3) / 4, 256, 0, stream>>>(u1, set_feat, offs, b_vc, g_set, be_set, out_set, setb);
  gemm_m97_k<0><<<122 * 4, 256, 0, stream>>>(setb, w_vs_b, proj, nullptr, MS, ND, ND);
  cand_ln_k<<<(MC + 3) / 4, 256, 0, stream>>>(cand_feat, proj, cidx, b_vs, g_cand, be_cand, candh);
  gemm_m97_k<1><<<365 * 8, 256, 0, stream>>>(candh, w1_b, h1, ff_b1, MC, ND2, ND);
  // FF2 in 3 M-chunks: GEMM (bias -> bf16) into setb region, then fused resid+LN.
  // Stream ordering serializes chunk i+1's GEMM after chunk i's LN (buffer reuse safe).
  for (int c = 0; c < 3; ++c) {
    const u16* h1c   = h1 + (size_t)c * MCH * ND2;
    const u16* residc= candh + (size_t)c * MCH * ND;
    float* outc      = out_cand + (size_t)c * MCH * ND;
    gemm_m97_k<2><<<122 * 4, 256, 0, stream>>>(h1c, w2_b, h2chunk, ff_b2, MCH, ND, ND2);
    ln_ff_k<<<(MCH + 3) / 4, 256, 0, stream>>>(h2chunk, residc, g_ff, be_ff, outc, MCH);
  }
}

// Round 6
// 402.719 us; speedup vs baseline: 1.2397x; 1.2397x over previous
//
#include <hip/hip_runtime.h>

using u16 = unsigned short;
using u32 = unsigned int;

typedef __attribute__((ext_vector_type(8))) short bf16x8;   // 8 bf16 (4 VGPRs) MFMA frag
typedef __attribute__((ext_vector_type(4))) float f32x4;
typedef __attribute__((ext_vector_type(8))) u16 u16x8;
typedef __attribute__((ext_vector_type(4))) u16 u16x4;

constexpr int NB = 64, NC = 729, NS = 243, ND = 512, ND2 = 1024;
constexpr int MS = NB * NS;   // 15552 set rows
constexpr int MC = NB * NC;   // 46656 cand rows
constexpr int MCH = MC / 3;   // 15552 rows per FF2 chunk

__device__ __forceinline__ u16 f2bf(float f) {
  u32 u = __builtin_bit_cast(u32, f);
  return (u16)((u + 0x7fffu + ((u >> 16) & 1u)) >> 16);   // RNE
}
__device__ __forceinline__ float bf2f(u16 h) {
  return __builtin_bit_cast(float, (u32)h << 16);
}
__device__ __forceinline__ void gload16(const void* g, void* l) {
  __builtin_amdgcn_global_load_lds((const __attribute__((address_space(1))) u32*)g,
                                   (__attribute__((address_space(3))) u32*)l, 16, 0, 0);
}

// ---------------- weight f32 -> bf16 cast ----------------
__global__ __launch_bounds__(256) void cast_bf16_k(const float* __restrict__ in,
                                                   u16* __restrict__ out, int n4) {
  int i = blockIdx.x * 256 + threadIdx.x;
  if (i >= n4) return;
  f32x4 v = ((const f32x4*)in)[i];
  u16x4 o;
  o.x = f2bf(v.x); o.y = f2bf(v.y); o.z = f2bf(v.z); o.w = f2bf(v.w);
  ((u16x4*)out)[i] = o;
}

// ---------------- CSR build: register-only ranks (no LDS latency chains) ----------------
// list order within each set == entry order (bit-identical downstream sums).
// Step A: per-64-chunk rank via 64-step __shfl loop (register ops only).
// Step B: 35-chunk exclusive prefix per set. Step C: 256-slot scan for offsets.
__global__ __launch_bounds__(1024) void build_csr_k(const int* __restrict__ idx,
                                                    int* __restrict__ offs,
                                                    int* __restrict__ list) {
  constexpr int NE = 3 * NC;              // 2187 entries
  constexpr int NCH = (NE + 63) / 64;     // 35 chunks
  __shared__ int sidx[NE];                // 8748 B
  __shared__ int lrank[NE];               // 8748 B
  __shared__ int hist[NCH][NS];           // 34020 B
  __shared__ int scan[256];               // 1024 B
  __shared__ int soffs[NS];               // 972 B
  const int t = threadIdx.x;
  const int wv = t >> 6, ln = t & 63;

  for (int e = t; e < NE; e += 1024) sidx[e] = idx[e];
  for (int i = t; i < NCH * NS; i += 1024) (&hist[0][0])[i] = 0;
  __syncthreads();

  // Step A: rank within chunk + per-chunk per-set counts (register-only inner loop)
  for (int c = wv; c < NCH; c += 16) {
    int e = c * 64 + ln;
    int s = (e < NE) ? sidx[e] : -1;
    int rank = 0, tot = 0;
#pragma unroll
    for (int l2 = 0; l2 < 64; ++l2) {
      int v = __shfl(s, l2);
      bool m = (v == s) && (s >= 0);
      rank += (m && (l2 < ln)) ? 1 : 0;
      tot  += m ? 1 : 0;
    }
    if (e < NE) {
      lrank[e] = rank;
      if (rank == 0) hist[c][s] = tot;   // single writer per (c,s)
    }
  }
  __syncthreads();

  // Step B: exclusive prefix over chunks, per set; total -> scan[s]
  int mycnt = 0;
  if (t < NS) {
    int run = 0;
#pragma unroll 5
    for (int c = 0; c < NCH; ++c) { int v = hist[c][t]; hist[c][t] = run; run += v; }
    mycnt = run;
  }
  if (t < 256) scan[t] = (t < NS) ? mycnt : 0;
  __syncthreads();

  // Step C: inclusive Hillis-Steele scan over 256 slots (all threads hit barriers)
  for (int d = 1; d < 256; d <<= 1) {
    int v = 0;
    if (t < 256 && t >= d) v = scan[t - d];
    __syncthreads();
    if (t < 256) scan[t] += v;
    __syncthreads();
  }
  if (t < NS) {
    soffs[t] = scan[t] - mycnt;          // exclusive offset
    offs[t] = scan[t] - mycnt;
  }
  if (t == 0) offs[NS] = NE;
  __syncthreads();

  // Step D: scatter list entries
  for (int e = t; e < NE; e += 1024) {
    int s = sidx[e];
    list[soffs[s] + hist[e >> 6][s] + lrank[e]] = e / 3;   // c = e/3 (repeat(3))
  }
}

// ---------------- per-set aggregation of cand_feat (pre-GEMM1 scatter) ----------------
__global__ __launch_bounds__(256) void agg_k(const float* __restrict__ cand_feat,
                                             const int* __restrict__ offs,
                                             const int* __restrict__ list,
                                             u16* __restrict__ agg) {
  int row = blockIdx.x * 4 + (threadIdx.x >> 6);
  if (row >= MS) return;
  int lane = threadIdx.x & 63;
  int b = row / NS, s = row - b * NS;
  int e0 = offs[s], e1 = offs[s + 1];
  const float* base = cand_feat + (size_t)b * NC * ND + lane * 8;
  f32x4 a0 = {0.f, 0.f, 0.f, 0.f}, a1 = {0.f, 0.f, 0.f, 0.f};
  for (int e = e0; e < e1; ++e) {
    const float* p = base + (size_t)list[e] * ND;
    a0 += *(const f32x4*)p;
    a1 += *(const f32x4*)(p + 4);
  }
  u16x8 o;
  o[0] = f2bf(a0.x); o[1] = f2bf(a0.y); o[2] = f2bf(a0.z); o[3] = f2bf(a0.w);
  o[4] = f2bf(a1.x); o[5] = f2bf(a1.y); o[6] = f2bf(a1.z); o[7] = f2bf(a1.w);
  *(u16x8*)(agg + (size_t)row * ND + lane * 8) = o;
}

// ============ m97-structure 128x128 bf16 GEMM, C = A @ B^T ============
// BK=32, single-buffer 16KB LDS, 256 threads, 3 blocks/CU (inter-block overlap
// hides barrier drains — m97/m114). Coalesced 64B-row staging with
// s(row)=(row^(row>>2))&3 chunk swizzle (pre-swizzled global source, linear
// LDS dest) -> conflict-free ds_read_b128.
// EP=0: f32, no bias.  EP=1: bias+relu -> bf16.  EP=2: bias -> bf16.
template <int EP>
__global__ __launch_bounds__(256, 3) void gemm_m97_k(const u16* __restrict__ A,
                                                     const u16* __restrict__ Bw,
                                                     void* __restrict__ Out,
                                                     const float* __restrict__ bias,
                                                     int M, int N, int K) {
  constexpr int BK = 32;
  __shared__ u16 lA[128 * BK];   // 8 KB, [row][4 chunks of 8 elems]
  __shared__ u16 lB[128 * BK];   // 8 KB
  const int t = threadIdx.x, wid = t >> 6, lane = t & 63;
  const int MT = (M + 127) >> 7;
  const int mt = blockIdx.x % MT, nt = blockIdx.x / MT;
  const int m0 = mt << 7, n0 = nt << 7;

  const int srow = t >> 2, sc = t & 3;                       // srow 0..63
  const int cp = (sc ^ ((srow ^ (srow >> 2)) & 3)) * 8;      // swizzled src chunk
  int ra0 = m0 + srow;       if (ra0 > M - 1) ra0 = M - 1;   // tail clamp (A only)
  int ra1 = m0 + 64 + srow;  if (ra1 > M - 1) ra1 = M - 1;
  const u16* gA0 = A + (size_t)ra0 * K + cp;
  const u16* gA1 = A + (size_t)ra1 * K + cp;
  const u16* gB0 = Bw + (size_t)(n0 + srow) * K + cp;
  const u16* gB1 = Bw + (size_t)(n0 + 64 + srow) * K + cp;

  const int li = lane & 15, g0 = lane >> 4;
  const int sw = (li ^ (li >> 2)) & 3;
  const int wr = wid >> 1, wc = wid & 1;
  const int aBase = (wr * 64 + li) * BK + ((g0 ^ sw) << 3);
  const int bBase = (wc * 64 + li) * BK + ((g0 ^ sw) << 3);

  f32x4 acc[4][4] = {};

  for (int kt = 0; kt < K; kt += BK) {
    gload16(gA0, lA + t * 8); gload16(gA1, lA + t * 8 + 2048);
    gload16(gB0, lB + t * 8); gload16(gB1, lB + t * 8 + 2048);
    gA0 += BK; gA1 += BK; gB0 += BK; gB1 += BK;
    __syncthreads();
    bf16x8 af[4], bfr[4];
#pragma unroll
    for (int i = 0; i < 4; ++i) {
      af[i]  = *(const bf16x8*)(lA + aBase + i * 512);
      bfr[i] = *(const bf16x8*)(lB + bBase + i * 512);
    }
#pragma unroll
    for (int mi = 0; mi < 4; ++mi)
#pragma unroll
      for (int ni = 0; ni < 4; ++ni)
        acc[mi][ni] = __builtin_amdgcn_mfma_f32_16x16x32_bf16(af[mi], bfr[ni], acc[mi][ni], 0, 0, 0);
    __syncthreads();
  }

  const int rb = m0 + wr * 64 + (g0 << 2);
  const int cb = n0 + wc * 64 + li;
  if (EP == 0) {
    float* O = (float*)Out;
#pragma unroll
    for (int mi = 0; mi < 4; ++mi)
#pragma unroll
      for (int ni = 0; ni < 4; ++ni) {
        int cc = cb + ni * 16;
#pragma unroll
        for (int r = 0; r < 4; ++r) {
          int rr = rb + mi * 16 + r;
          if (rr < M) O[(size_t)rr * N + cc] = acc[mi][ni][r];
        }
      }
  } else {
    u16* O = (u16*)Out;
    float bv[4];
#pragma unroll
    for (int ni = 0; ni < 4; ++ni) bv[ni] = bias[cb + ni * 16];
#pragma unroll
    for (int mi = 0; mi < 4; ++mi)
#pragma unroll
      for (int ni = 0; ni < 4; ++ni) {
        int cc = cb + ni * 16;
#pragma unroll
        for (int r = 0; r < 4; ++r) {
          int rr = rb + mi * 16 + r;
          float v = acc[mi][ni][r] + bv[ni];
          if (EP == 1) v = fmaxf(v, 0.0f);
          if (rr < M) O[(size_t)rr * N + cc] = f2bf(v);
        }
      }
  }
}

// ---------------- set LN: set_out = LN(set_feat + (u1 + cnt*b_vc)/9) ----------------
__global__ __launch_bounds__(256) void set_ln_k(const float* __restrict__ u1,
                                                const float* __restrict__ set_feat,
                                                const int* __restrict__ offs,
                                                const float* __restrict__ b_vc,
                                                const float* __restrict__ gam,
                                                const float* __restrict__ bet,
                                                float* __restrict__ set_out,
                                                u16* __restrict__ set_out_bf) {
  int row = blockIdx.x * 4 + (threadIdx.x >> 6);
  if (row >= MS) return;
  int lane = threadIdx.x & 63;
  int s = row % NS;
  float c9 = (float)(offs[s + 1] - offs[s]) * (1.0f / 9.0f);
  size_t base = (size_t)row * ND + lane * 8;
  f32x4 u0 = *(const f32x4*)(u1 + base),       u1b = *(const f32x4*)(u1 + base + 4);
  f32x4 s0 = *(const f32x4*)(set_feat + base), s1  = *(const f32x4*)(set_feat + base + 4);
  f32x4 b0 = *(const f32x4*)(b_vc + lane * 8), b1  = *(const f32x4*)(b_vc + lane * 8 + 4);
  f32x4 x0 = s0 + u0 * (1.0f / 9.0f) + b0 * c9;
  f32x4 x1 = s1 + u1b * (1.0f / 9.0f) + b1 * c9;
  float sm = 0.f, sq = 0.f;
#pragma unroll
  for (int i = 0; i < 4; ++i) { sm += x0[i] + x1[i]; sq += x0[i] * x0[i] + x1[i] * x1[i]; }
#pragma unroll
  for (int m = 32; m; m >>= 1) { sm += __shfl_xor(sm, m); sq += __shfl_xor(sq, m); }
  float mu = sm * (1.0f / ND);
  float rs = rsqrtf(sq * (1.0f / ND) - mu * mu + 1e-5f);
  f32x4 g0 = *(const f32x4*)(gam + lane * 8), g1 = *(const f32x4*)(gam + lane * 8 + 4);
  f32x4 e0 = *(const f32x4*)(bet + lane * 8), e1 = *(const f32x4*)(bet + lane * 8 + 4);
  f32x4 y0, y1; u16x8 ob;
#pragma unroll
  for (int i = 0; i < 4; ++i) {
    y0[i] = (x0[i] - mu) * rs * g0[i] + e0[i];
    y1[i] = (x1[i] - mu) * rs * g1[i] + e1[i];
    ob[i] = f2bf(y0[i]); ob[i + 4] = f2bf(y1[i]);
  }
  *(f32x4*)(set_out + base) = y0;
  *(f32x4*)(set_out + base + 4) = y1;
  *(u16x8*)(set_out_bf + base) = ob;
}

// ---------------- cand LN: cand_h = LN(cand_feat + mean3(proj) + b_vs) ----------------
__global__ __launch_bounds__(256) void cand_ln_k(const float* __restrict__ cand_feat,
                                                 const float* __restrict__ proj,
                                                 const int* __restrict__ cidx,
                                                 const float* __restrict__ b_vs,
                                                 const float* __restrict__ gam,
                                                 const float* __restrict__ bet,
                                                 u16* __restrict__ cand_h) {
  int row = blockIdx.x * 4 + (threadIdx.x >> 6);
  if (row >= MC) return;
  int lane = threadIdx.x & 63;
  int b = row / NC, c = row - b * NC;
  int i0 = cidx[c * 3], i1 = cidx[c * 3 + 1], i2 = cidx[c * 3 + 2];
  const float* pb = proj + (size_t)b * NS * ND + lane * 8;
  f32x4 p00 = *(const f32x4*)(pb + (size_t)i0 * ND), p01 = *(const f32x4*)(pb + (size_t)i0 * ND + 4);
  f32x4 p10 = *(const f32x4*)(pb + (size_t)i1 * ND), p11 = *(const f32x4*)(pb + (size_t)i1 * ND + 4);
  f32x4 p20 = *(const f32x4*)(pb + (size_t)i2 * ND), p21 = *(const f32x4*)(pb + (size_t)i2 * ND + 4);
  size_t base = (size_t)row * ND + lane * 8;
  f32x4 c0 = *(const f32x4*)(cand_feat + base), c1 = *(const f32x4*)(cand_feat + base + 4);
  f32x4 v0 = *(const f32x4*)(b_vs + lane * 8),  v1 = *(const f32x4*)(b_vs + lane * 8 + 4);
  const float third = 1.0f / 3.0f;
  f32x4 x0 = c0 + (p00 + p10 + p20) * third + v0;
  f32x4 x1 = c1 + (p01 + p11 + p21) * third + v1;
  float sm = 0.f, sq = 0.f;
#pragma unroll
  for (int i = 0; i < 4; ++i) { sm += x0[i] + x1[i]; sq += x0[i] * x0[i] + x1[i] * x1[i]; }
#pragma unroll
  for (int m = 32; m; m >>= 1) { sm += __shfl_xor(sm, m); sq += __shfl_xor(sq, m); }
  float mu = sm * (1.0f / ND);
  float rs = rsqrtf(sq * (1.0f / ND) - mu * mu + 1e-5f);
  f32x4 g0 = *(const f32x4*)(gam + lane * 8), g1 = *(const f32x4*)(gam + lane * 8 + 4);
  f32x4 e0 = *(const f32x4*)(bet + lane * 8), e1 = *(const f32x4*)(bet + lane * 8 + 4);
  u16x8 ob;
#pragma unroll
  for (int i = 0; i < 4; ++i) {
    ob[i]     = f2bf((x0[i] - mu) * rs * g0[i] + e0[i]);
    ob[i + 4] = f2bf((x1[i] - mu) * rs * g1[i] + e1[i]);
  }
  *(u16x8*)(cand_h + base) = ob;
}

// ---------------- final LN: out = LN(cand_h + h2b) (bias folded into h2b) ----------------
__global__ __launch_bounds__(256) void ln_ff_k(const u16* __restrict__ h2b,
                                               const u16* __restrict__ resid,
                                               const float* __restrict__ gam,
                                               const float* __restrict__ bet,
                                               float* __restrict__ out, int nrows) {
  int row = blockIdx.x * 4 + (threadIdx.x >> 6);
  if (row >= nrows) return;
  int lane = threadIdx.x & 63;
  size_t base = (size_t)row * ND + lane * 8;
  u16x8 ha = *(const u16x8*)(h2b + base);
  u16x8 ra = *(const u16x8*)(resid + base);
  float x[8];
  float sm = 0.f, sq = 0.f;
#pragma unroll
  for (int i = 0; i < 8; ++i) {
    x[i] = bf2f(ha[i]) + bf2f(ra[i]);
    sm += x[i]; sq += x[i] * x[i];
  }
#pragma unroll
  for (int m = 32; m; m >>= 1) { sm += __shfl_xor(sm, m); sq += __shfl_xor(sq, m); }
  float mu = sm * (1.0f / ND);
  float rs = rsqrtf(sq * (1.0f / ND) - mu * mu + 1e-5f);
  f32x4 g0 = *(const f32x4*)(gam + lane * 8), g1 = *(const f32x4*)(gam + lane * 8 + 4);
  f32x4 e0 = *(const f32x4*)(bet + lane * 8), e1 = *(const f32x4*)(bet + lane * 8 + 4);
  f32x4 y0, y1;
#pragma unroll
  for (int i = 0; i < 4; ++i) {
    y0[i] = (x[i] - mu) * rs * g0[i] + e0[i];
    y1[i] = (x[i + 4] - mu) * rs * g1[i] + e1[i];
  }
  *(f32x4*)(out + base) = y0;
  *(f32x4*)(out + base + 4) = y1;
}

// ---------------- launcher ----------------
extern "C" void kernel_launch(void* const* d_in, const int* in_sizes, int n_in,
                              void* d_out, int out_size, void* d_ws, size_t ws_size,
                              hipStream_t stream) {
  const float* cand_feat = (const float*)d_in[0];
  const float* set_feat  = (const float*)d_in[1];
  const float* W_vc  = (const float*)d_in[2];
  const float* b_vc  = (const float*)d_in[3];
  const float* W_vs  = (const float*)d_in[4];
  const float* b_vs  = (const float*)d_in[5];
  const float* ff_W1 = (const float*)d_in[6];
  const float* ff_b1 = (const float*)d_in[7];
  const float* ff_W2 = (const float*)d_in[8];
  const float* ff_b2 = (const float*)d_in[9];
  const float* g_set  = (const float*)d_in[10];
  const float* be_set = (const float*)d_in[11];
  const float* g_cand = (const float*)d_in[12];
  const float* be_cand= (const float*)d_in[13];
  const float* g_ff   = (const float*)d_in[14];
  const float* be_ff  = (const float*)d_in[15];
  const int*   cidx   = (const int*)d_in[16];
  (void)in_sizes; (void)n_in; (void)out_size; (void)ws_size;

  // workspace layout (max used: ~68MB)
  char* ws = (char*)d_ws;
  u16* w_vc_b = (u16*)(ws + 0);
  u16* w_vs_b = (u16*)(ws + (512 << 10));
  u16* w1_b   = (u16*)(ws + (1 << 20));
  u16* w2_b   = (u16*)(ws + (2 << 20));
  int* offs   = (int*)(ws + (3 << 20));
  int* list   = (int*)(ws + (3 << 20) + 4096);
  u16* setb   = (u16*)(ws + (4 << 20));        // 15.9 MB  set_out bf16; later FF2 h2 chunk
  u16* candh  = (u16*)(ws + (20 << 20));       // 47.8 MB  cand_h bf16 (ends ~67.8MB)
  u16* h2chunk = setb;                         // reuse: setb dead after GEMM2

  // d_out region reuse (cand region = 95.55 MB, written last):
  float* out_cand = (float*)d_out;
  float* out_set  = out_cand + (size_t)MC * ND;
  u16*   agg  = (u16*)out_set;     // 15.9 MB, dead before set_out written
  float* u1   = out_cand;          // GEMM1 out, dead after set_ln
  float* proj = out_cand;          // GEMM2 out, dead after cand_ln
  u16*   h1   = (u16*)out_cand;    // FF1 out (46656 x 1024 bf16 = exactly the cand region)

  cast_bf16_k<<<(ND * ND / 4 + 255) / 256, 256, 0, stream>>>(W_vc, w_vc_b, ND * ND / 4);
  cast_bf16_k<<<(ND * ND / 4 + 255) / 256, 256, 0, stream>>>(W_vs, w_vs_b, ND * ND / 4);
  cast_bf16_k<<<(ND2 * ND / 4 + 255) / 256, 256, 0, stream>>>(ff_W1, w1_b, ND2 * ND / 4);
  cast_bf16_k<<<(ND * ND2 / 4 + 255) / 256, 256, 0, stream>>>(ff_W2, w2_b, ND * ND2 / 4);
  build_csr_k<<<1, 1024, 0, stream>>>(cidx, offs, list);
  agg_k<<<(MS + 3) / 4, 256, 0, stream>>>(cand_feat, offs, list, agg);
  gemm_m97_k<0><<<122 * 4, 256, 0, stream>>>(agg, w_vc_b, u1, nullptr, MS, ND, ND);
  set_ln_k<<<(MS + 3) / 4, 256, 0, stream>>>(u1, set_feat, offs, b_vc, g_set, be_set, out_set, setb);
  gemm_m97_k<0><<<122 * 4, 256, 0, stream>>>(setb, w_vs_b, proj, nullptr, MS, ND, ND);
  cand_ln_k<<<(MC + 3) / 4, 256, 0, stream>>>(cand_feat, proj, cidx, b_vs, g_cand, be_cand, candh);
  gemm_m97_k<1><<<365 * 8, 256, 0, stream>>>(candh, w1_b, h1, ff_b1, MC, ND2, ND);
  // FF2 in 3 M-chunks: GEMM (bias -> bf16) into setb region, then fused resid+LN.
  for (int c = 0; c < 3; ++c) {
    const u16* h1c   = h1 + (size_t)c * MCH * ND2;
    const u16* residc= candh + (size_t)c * MCH * ND;
    float* outc      = out_cand + (size_t)c * MCH * ND;
    gemm_m97_k<2><<<122 * 4, 256, 0, stream>>>(h1c, w2_b, h2chunk, ff_b2, MCH, ND, ND2);
    ln_ff_k<<<(MCH + 3) / 4, 256, 0, stream>>>(h2chunk, residc, g_ff, be_ff, outc, MCH);
  }
}

// Round 7
// 373.011 us; speedup vs baseline: 1.3384x; 1.0796x over previous
//
#include <hip/hip_runtime.h>

using u16 = unsigned short;
using u32 = unsigned int;

typedef __attribute__((ext_vector_type(8))) short bf16x8;   // 8 bf16 (4 VGPRs) MFMA frag
typedef __attribute__((ext_vector_type(4))) float f32x4;
typedef __attribute__((ext_vector_type(8))) u16 u16x8;
typedef __attribute__((ext_vector_type(4))) u16 u16x4;

constexpr int NB = 64, NC = 729, NS = 243, ND = 512, ND2 = 1024;
constexpr int MS = NB * NS;   // 15552 set rows
constexpr int MC = NB * NC;   // 46656 cand rows
constexpr int MCH = MC / 3;   // 15552 rows per FF2 chunk

__device__ __forceinline__ u16 f2bf(float f) {
  u32 u = __builtin_bit_cast(u32, f);
  return (u16)((u + 0x7fffu + ((u >> 16) & 1u)) >> 16);   // RNE
}
__device__ __forceinline__ float bf2f(u16 h) {
  return __builtin_bit_cast(float, (u32)h << 16);
}
__device__ __forceinline__ void gload16(const void* g, void* l) {
  __builtin_amdgcn_global_load_lds((const __attribute__((address_space(1))) u32*)g,
                                   (__attribute__((address_space(3))) u32*)l, 16, 0, 0);
}

// ---------------- weight f32 -> bf16 cast ----------------
__global__ __launch_bounds__(256) void cast_bf16_k(const float* __restrict__ in,
                                                   u16* __restrict__ out, int n4) {
  int i = blockIdx.x * 256 + threadIdx.x;
  if (i >= n4) return;
  f32x4 v = ((const f32x4*)in)[i];
  u16x4 o;
  o.x = f2bf(v.x); o.y = f2bf(v.y); o.z = f2bf(v.z); o.w = f2bf(v.w);
  ((u16x4*)out)[i] = o;
}

// ---------------- CSR build: register-only ranks (no LDS latency chains) ----------------
__global__ __launch_bounds__(1024) void build_csr_k(const int* __restrict__ idx,
                                                    int* __restrict__ offs,
                                                    int* __restrict__ list) {
  constexpr int NE = 3 * NC;              // 2187 entries
  constexpr int NCH = (NE + 63) / 64;     // 35 chunks
  __shared__ int sidx[NE];
  __shared__ int lrank[NE];
  __shared__ int hist[NCH][NS];
  __shared__ int scan[256];
  __shared__ int soffs[NS];
  const int t = threadIdx.x;
  const int wv = t >> 6, ln = t & 63;

  for (int e = t; e < NE; e += 1024) sidx[e] = idx[e];
  for (int i = t; i < NCH * NS; i += 1024) (&hist[0][0])[i] = 0;
  __syncthreads();

  for (int c = wv; c < NCH; c += 16) {
    int e = c * 64 + ln;
    int s = (e < NE) ? sidx[e] : -1;
    int rank = 0, tot = 0;
#pragma unroll
    for (int l2 = 0; l2 < 64; ++l2) {
      int v = __shfl(s, l2);
      bool m = (v == s) && (s >= 0);
      rank += (m && (l2 < ln)) ? 1 : 0;
      tot  += m ? 1 : 0;
    }
    if (e < NE) {
      lrank[e] = rank;
      if (rank == 0) hist[c][s] = tot;
    }
  }
  __syncthreads();

  int mycnt = 0;
  if (t < NS) {
    int run = 0;
#pragma unroll 5
    for (int c = 0; c < NCH; ++c) { int v = hist[c][t]; hist[c][t] = run; run += v; }
    mycnt = run;
  }
  if (t < 256) scan[t] = (t < NS) ? mycnt : 0;
  __syncthreads();

  for (int d = 1; d < 256; d <<= 1) {
    int v = 0;
    if (t < 256 && t >= d) v = scan[t - d];
    __syncthreads();
    if (t < 256) scan[t] += v;
    __syncthreads();
  }
  if (t < NS) {
    soffs[t] = scan[t] - mycnt;
    offs[t] = scan[t] - mycnt;
  }
  if (t == 0) offs[NS] = NE;
  __syncthreads();

  for (int e = t; e < NE; e += 1024) {
    int s = sidx[e];
    list[soffs[s] + hist[e >> 6][s] + lrank[e]] = e / 3;
  }
}

// ---------------- per-set aggregation of cand_feat (pre-GEMM1 scatter) ----------------
__global__ __launch_bounds__(256) void agg_k(const float* __restrict__ cand_feat,
                                             const int* __restrict__ offs,
                                             const int* __restrict__ list,
                                             u16* __restrict__ agg) {
  int row = blockIdx.x * 4 + (threadIdx.x >> 6);
  if (row >= MS) return;
  int lane = threadIdx.x & 63;
  int b = row / NS, s = row - b * NS;
  int e0 = offs[s], e1 = offs[s + 1];
  const float* base = cand_feat + (size_t)b * NC * ND + lane * 8;
  f32x4 a0 = {0.f, 0.f, 0.f, 0.f}, a1 = {0.f, 0.f, 0.f, 0.f};
  for (int e = e0; e < e1; ++e) {
    const float* p = base + (size_t)list[e] * ND;
    a0 += *(const f32x4*)p;
    a1 += *(const f32x4*)(p + 4);
  }
  u16x8 o;
  o[0] = f2bf(a0.x); o[1] = f2bf(a0.y); o[2] = f2bf(a0.z); o[3] = f2bf(a0.w);
  o[4] = f2bf(a1.x); o[5] = f2bf(a1.y); o[6] = f2bf(a1.z); o[7] = f2bf(a1.w);
  *(u16x8*)(agg + (size_t)row * ND + lane * 8) = o;
}

// ============ 128x128 bf16 GEMM v4, C = A @ B^T ============
// BK=64 (128B rows = 8 x 16B slots), full 3-bit XOR swizzle slot = chunk ^ (row&7)
// (G4-validated pattern): pre-swizzled global src, linear global_load_lds dest,
// swizzled ds_read_b128 -> 2 lanes/quad per quarter-wave (minimum). Single-buffer
// 32KB LDS, 3 blocks/CU. Supertile order (mt=wg/NT: consecutive blocks share the
// A-panel) + bijective XCD swizzle (grid % 8 == 0).
// EP=0: f32, no bias.  EP=1: bias+relu -> bf16.  EP=2: bias -> bf16.
template <int EP>
__global__ __launch_bounds__(256, 3) void gemm_k64(const u16* __restrict__ A,
                                                   const u16* __restrict__ Bw,
                                                   void* __restrict__ Out,
                                                   const float* __restrict__ bias,
                                                   int M, int N, int K) {
  constexpr int BK = 64;
  __shared__ u16 lA[128 * BK];   // 16 KB
  __shared__ u16 lB[128 * BK];   // 16 KB
  const int t = threadIdx.x, wid = t >> 6, lane = t & 63;
  const int NT = N >> 7;
  const int nwg = gridDim.x, cpx = nwg >> 3;
  int wg = blockIdx.x;
  wg = (wg & 7) * cpx + (wg >> 3);           // bijective XCD swizzle (nwg%8==0)
  const int mt = wg / NT, nt = wg % NT;
  const int m0 = mt << 7, n0 = nt << 7;

  // staging: 4 issues each for A,B; chunk-slot s = i*256+t; row=s>>3, slot=s&7
  const u16* gA[4]; const u16* gB[4]; int ldo[4];
#pragma unroll
  for (int i = 0; i < 4; ++i) {
    int s = i * 256 + t;
    int r = s >> 3, j = s & 7;
    int cj = (j ^ (r & 7)) * 8;              // pre-swizzled source chunk (elements)
    int ar = m0 + r; if (ar > M - 1) ar = M - 1;   // tail clamp (A only)
    gA[i] = A + (size_t)ar * K + cj;
    gB[i] = Bw + (size_t)(n0 + r) * K + cj;
    ldo[i] = s * 8;                          // linear LDS dest (elements)
  }

  const int li = lane & 15, g0 = lane >> 4;
  const int wr = wid >> 1, wc = wid & 1;
  // frag read addr (elements): row*64 + ((chunk ^ (row&7))<<3); row&7 == li&7
  int aOff[4], bOff[4];
#pragma unroll
  for (int i = 0; i < 4; ++i) {
    int rowA = wr * 64 + i * 16 + li;
    int rowB = wc * 64 + i * 16 + li;
    aOff[i] = rowA * 64 + ((g0 ^ (li & 7)) << 3);
    bOff[i] = rowB * 64 + ((g0 ^ (li & 7)) << 3);
  }

  f32x4 acc[4][4] = {};

  for (int kt = 0; kt < K; kt += BK) {
#pragma unroll
    for (int i = 0; i < 4; ++i) gload16(gA[i], lA + ldo[i]);
#pragma unroll
    for (int i = 0; i < 4; ++i) gload16(gB[i], lB + ldo[i]);
#pragma unroll
    for (int i = 0; i < 4; ++i) { gA[i] += BK; gB[i] += BK; }
    __syncthreads();
#pragma unroll
    for (int kk = 0; kk < 2; ++kk) {
      // chunk = kk*4 + g0 ; slot = chunk ^ (li&7) ; kk flips bit2 of slot -> addr ^ 32
      bf16x8 af[4], bfr[4];
#pragma unroll
      for (int i = 0; i < 4; ++i) {
        af[i]  = *(const bf16x8*)(lA + (aOff[i] ^ (kk << 5)));
        bfr[i] = *(const bf16x8*)(lB + (bOff[i] ^ (kk << 5)));
      }
#pragma unroll
      for (int mi = 0; mi < 4; ++mi)
#pragma unroll
        for (int ni = 0; ni < 4; ++ni)
          acc[mi][ni] = __builtin_amdgcn_mfma_f32_16x16x32_bf16(af[mi], bfr[ni], acc[mi][ni], 0, 0, 0);
    }
    __syncthreads();
  }

  const int rb = m0 + wr * 64 + (g0 << 2);
  const int cb = n0 + wc * 64 + li;
  if (EP == 0) {
    float* O = (float*)Out;
#pragma unroll
    for (int mi = 0; mi < 4; ++mi)
#pragma unroll
      for (int ni = 0; ni < 4; ++ni) {
        int cc = cb + ni * 16;
#pragma unroll
        for (int r = 0; r < 4; ++r) {
          int rr = rb + mi * 16 + r;
          if (rr < M) O[(size_t)rr * N + cc] = acc[mi][ni][r];
        }
      }
  } else {
    u16* O = (u16*)Out;
    float bv[4];
#pragma unroll
    for (int ni = 0; ni < 4; ++ni) bv[ni] = bias[cb + ni * 16];
#pragma unroll
    for (int mi = 0; mi < 4; ++mi)
#pragma unroll
      for (int ni = 0; ni < 4; ++ni) {
        int cc = cb + ni * 16;
#pragma unroll
        for (int r = 0; r < 4; ++r) {
          int rr = rb + mi * 16 + r;
          float v = acc[mi][ni][r] + bv[ni];
          if (EP == 1) v = fmaxf(v, 0.0f);
          if (rr < M) O[(size_t)rr * N + cc] = f2bf(v);
        }
      }
  }
}

// ---------------- set LN: set_out = LN(set_feat + (u1 + cnt*b_vc)/9) ----------------
__global__ __launch_bounds__(256) void set_ln_k(const float* __restrict__ u1,
                                                const float* __restrict__ set_feat,
                                                const int* __restrict__ offs,
                                                const float* __restrict__ b_vc,
                                                const float* __restrict__ gam,
                                                const float* __restrict__ bet,
                                                float* __restrict__ set_out,
                                                u16* __restrict__ set_out_bf) {
  int row = blockIdx.x * 4 + (threadIdx.x >> 6);
  if (row >= MS) return;
  int lane = threadIdx.x & 63;
  int s = row % NS;
  float c9 = (float)(offs[s + 1] - offs[s]) * (1.0f / 9.0f);
  size_t base = (size_t)row * ND + lane * 8;
  f32x4 u0 = *(const f32x4*)(u1 + base),       u1b = *(const f32x4*)(u1 + base + 4);
  f32x4 s0 = *(const f32x4*)(set_feat + base), s1  = *(const f32x4*)(set_feat + base + 4);
  f32x4 b0 = *(const f32x4*)(b_vc + lane * 8), b1  = *(const f32x4*)(b_vc + lane * 8 + 4);
  f32x4 x0 = s0 + u0 * (1.0f / 9.0f) + b0 * c9;
  f32x4 x1 = s1 + u1b * (1.0f / 9.0f) + b1 * c9;
  float sm = 0.f, sq = 0.f;
#pragma unroll
  for (int i = 0; i < 4; ++i) { sm += x0[i] + x1[i]; sq += x0[i] * x0[i] + x1[i] * x1[i]; }
#pragma unroll
  for (int m = 32; m; m >>= 1) { sm += __shfl_xor(sm, m); sq += __shfl_xor(sq, m); }
  float mu = sm * (1.0f / ND);
  float rs = rsqrtf(sq * (1.0f / ND) - mu * mu + 1e-5f);
  f32x4 g0 = *(const f32x4*)(gam + lane * 8), g1 = *(const f32x4*)(gam + lane * 8 + 4);
  f32x4 e0 = *(const f32x4*)(bet + lane * 8), e1 = *(const f32x4*)(bet + lane * 8 + 4);
  f32x4 y0, y1; u16x8 ob;
#pragma unroll
  for (int i = 0; i < 4; ++i) {
    y0[i] = (x0[i] - mu) * rs * g0[i] + e0[i];
    y1[i] = (x1[i] - mu) * rs * g1[i] + e1[i];
    ob[i] = f2bf(y0[i]); ob[i + 4] = f2bf(y1[i]);
  }
  *(f32x4*)(set_out + base) = y0;
  *(f32x4*)(set_out + base + 4) = y1;
  *(u16x8*)(set_out_bf + base) = ob;
}

// ---------------- cand LN: cand_h = LN(cand_feat + mean3(proj) + b_vs) ----------------
__global__ __launch_bounds__(256) void cand_ln_k(const float* __restrict__ cand_feat,
                                                 const float* __restrict__ proj,
                                                 const int* __restrict__ cidx,
                                                 const float* __restrict__ b_vs,
                                                 const float* __restrict__ gam,
                                                 const float* __restrict__ bet,
                                                 u16* __restrict__ cand_h) {
  int row = blockIdx.x * 4 + (threadIdx.x >> 6);
  if (row >= MC) return;
  int lane = threadIdx.x & 63;
  int b = row / NC, c = row - b * NC;
  int i0 = cidx[c * 3], i1 = cidx[c * 3 + 1], i2 = cidx[c * 3 + 2];
  const float* pb = proj + (size_t)b * NS * ND + lane * 8;
  f32x4 p00 = *(const f32x4*)(pb + (size_t)i0 * ND), p01 = *(const f32x4*)(pb + (size_t)i0 * ND + 4);
  f32x4 p10 = *(const f32x4*)(pb + (size_t)i1 * ND), p11 = *(const f32x4*)(pb + (size_t)i1 * ND + 4);
  f32x4 p20 = *(const f32x4*)(pb + (size_t)i2 * ND), p21 = *(const f32x4*)(pb + (size_t)i2 * ND + 4);
  size_t base = (size_t)row * ND + lane * 8;
  f32x4 c0 = *(const f32x4*)(cand_feat + base), c1 = *(const f32x4*)(cand_feat + base + 4);
  f32x4 v0 = *(const f32x4*)(b_vs + lane * 8),  v1 = *(const f32x4*)(b_vs + lane * 8 + 4);
  const float third = 1.0f / 3.0f;
  f32x4 x0 = c0 + (p00 + p10 + p20) * third + v0;
  f32x4 x1 = c1 + (p01 + p11 + p21) * third + v1;
  float sm = 0.f, sq = 0.f;
#pragma unroll
  for (int i = 0; i < 4; ++i) { sm += x0[i] + x1[i]; sq += x0[i] * x0[i] + x1[i] * x1[i]; }
#pragma unroll
  for (int m = 32; m; m >>= 1) { sm += __shfl_xor(sm, m); sq += __shfl_xor(sq, m); }
  float mu = sm * (1.0f / ND);
  float rs = rsqrtf(sq * (1.0f / ND) - mu * mu + 1e-5f);
  f32x4 g0 = *(const f32x4*)(gam + lane * 8), g1 = *(const f32x4*)(gam + lane * 8 + 4);
  f32x4 e0 = *(const f32x4*)(bet + lane * 8), e1 = *(const f32x4*)(bet + lane * 8 + 4);
  u16x8 ob;
#pragma unroll
  for (int i = 0; i < 4; ++i) {
    ob[i]     = f2bf((x0[i] - mu) * rs * g0[i] + e0[i]);
    ob[i + 4] = f2bf((x1[i] - mu) * rs * g1[i] + e1[i]);
  }
  *(u16x8*)(cand_h + base) = ob;
}

// ---------------- final LN: out = LN(cand_h + h2b) (bias folded into h2b) ----------------
__global__ __launch_bounds__(256) void ln_ff_k(const u16* __restrict__ h2b,
                                               const u16* __restrict__ resid,
                                               const float* __restrict__ gam,
                                               const float* __restrict__ bet,
                                               float* __restrict__ out, int nrows) {
  int row = blockIdx.x * 4 + (threadIdx.x >> 6);
  if (row >= nrows) return;
  int lane = threadIdx.x & 63;
  size_t base = (size_t)row * ND + lane * 8;
  u16x8 ha = *(const u16x8*)(h2b + base);
  u16x8 ra = *(const u16x8*)(resid + base);
  float x[8];
  float sm = 0.f, sq = 0.f;
#pragma unroll
  for (int i = 0; i < 8; ++i) {
    x[i] = bf2f(ha[i]) + bf2f(ra[i]);
    sm += x[i]; sq += x[i] * x[i];
  }
#pragma unroll
  for (int m = 32; m; m >>= 1) { sm += __shfl_xor(sm, m); sq += __shfl_xor(sq, m); }
  float mu = sm * (1.0f / ND);
  float rs = rsqrtf(sq * (1.0f / ND) - mu * mu + 1e-5f);
  f32x4 g0 = *(const f32x4*)(gam + lane * 8), g1 = *(const f32x4*)(gam + lane * 8 + 4);
  f32x4 e0 = *(const f32x4*)(bet + lane * 8), e1 = *(const f32x4*)(bet + lane * 8 + 4);
  f32x4 y0, y1;
#pragma unroll
  for (int i = 0; i < 4; ++i) {
    y0[i] = (x[i] - mu) * rs * g0[i] + e0[i];
    y1[i] = (x[i + 4] - mu) * rs * g1[i] + e1[i];
  }
  *(f32x4*)(out + base) = y0;
  *(f32x4*)(out + base + 4) = y1;
}

// ---------------- launcher ----------------
extern "C" void kernel_launch(void* const* d_in, const int* in_sizes, int n_in,
                              void* d_out, int out_size, void* d_ws, size_t ws_size,
                              hipStream_t stream) {
  const float* cand_feat = (const float*)d_in[0];
  const float* set_feat  = (const float*)d_in[1];
  const float* W_vc  = (const float*)d_in[2];
  const float* b_vc  = (const float*)d_in[3];
  const float* W_vs  = (const float*)d_in[4];
  const float* b_vs  = (const float*)d_in[5];
  const float* ff_W1 = (const float*)d_in[6];
  const float* ff_b1 = (const float*)d_in[7];
  const float* ff_W2 = (const float*)d_in[8];
  const float* ff_b2 = (const float*)d_in[9];
  const float* g_set  = (const float*)d_in[10];
  const float* be_set = (const float*)d_in[11];
  const float* g_cand = (const float*)d_in[12];
  const float* be_cand= (const float*)d_in[13];
  const float* g_ff   = (const float*)d_in[14];
  const float* be_ff  = (const float*)d_in[15];
  const int*   cidx   = (const int*)d_in[16];
  (void)in_sizes; (void)n_in; (void)out_size; (void)ws_size;

  // workspace layout (max used: ~68MB)
  char* ws = (char*)d_ws;
  u16* w_vc_b = (u16*)(ws + 0);
  u16* w_vs_b = (u16*)(ws + (512 << 10));
  u16* w1_b   = (u16*)(ws + (1 << 20));
  u16* w2_b   = (u16*)(ws + (2 << 20));
  int* offs   = (int*)(ws + (3 << 20));
  int* list   = (int*)(ws + (3 << 20) + 4096);
  u16* setb   = (u16*)(ws + (4 << 20));        // 15.9 MB  set_out bf16; later FF2 h2 chunk
  u16* candh  = (u16*)(ws + (20 << 20));       // 47.8 MB  cand_h bf16
  u16* h2chunk = setb;                         // reuse: setb dead after GEMM2

  // d_out region reuse (cand region = 95.55 MB, written last):
  float* out_cand = (float*)d_out;
  float* out_set  = out_cand + (size_t)MC * ND;
  u16*   agg  = (u16*)out_set;     // dead before set_out written
  float* u1   = out_cand;          // GEMM1 out, dead after set_ln
  float* proj = out_cand;          // GEMM2 out, dead after cand_ln
  u16*   h1   = (u16*)out_cand;    // FF1 out (46656 x 1024 bf16 = exactly the cand region)

  cast_bf16_k<<<(ND * ND / 4 + 255) / 256, 256, 0, stream>>>(W_vc, w_vc_b, ND * ND / 4);
  cast_bf16_k<<<(ND * ND / 4 + 255) / 256, 256, 0, stream>>>(W_vs, w_vs_b, ND * ND / 4);
  cast_bf16_k<<<(ND2 * ND / 4 + 255) / 256, 256, 0, stream>>>(ff_W1, w1_b, ND2 * ND / 4);
  cast_bf16_k<<<(ND * ND2 / 4 + 255) / 256, 256, 0, stream>>>(ff_W2, w2_b, ND * ND2 / 4);
  build_csr_k<<<1, 1024, 0, stream>>>(cidx, offs, list);
  agg_k<<<(MS + 3) / 4, 256, 0, stream>>>(cand_feat, offs, list, agg);
  gemm_k64<0><<<122 * 4, 256, 0, stream>>>(agg, w_vc_b, u1, nullptr, MS, ND, ND);
  set_ln_k<<<(MS + 3) / 4, 256, 0, stream>>>(u1, set_feat, offs, b_vc, g_set, be_set, out_set, setb);
  gemm_k64<0><<<122 * 4, 256, 0, stream>>>(setb, w_vs_b, proj, nullptr, MS, ND, ND);
  cand_ln_k<<<(MC + 3) / 4, 256, 0, stream>>>(cand_feat, proj, cidx, b_vs, g_cand, be_cand, candh);
  gemm_k64<1><<<365 * 8, 256, 0, stream>>>(candh, w1_b, h1, ff_b1, MC, ND2, ND);
  // FF2 in 3 M-chunks: GEMM (bias -> bf16) into setb region, then fused resid+LN.
  for (int c = 0; c < 3; ++c) {
    const u16* h1c   = h1 + (size_t)c * MCH * ND2;
    const u16* residc= candh + (size_t)c * MCH * ND;
    float* outc      = out_cand + (size_t)c * MCH * ND;
    gemm_k64<2><<<122 * 4, 256, 0, stream>>>(h1c, w2_b, h2chunk, ff_b2, MCH, ND, ND2);
    ln_ff_k<<<(MCH + 3) / 4, 256, 0, stream>>>(h2chunk, residc, g_ff, be_ff, outc, MCH);
  }
}

// Round 8
// 312.845 us; speedup vs baseline: 1.5958x; 1.1923x over previous
//
#include <hip/hip_runtime.h>

using u16 = unsigned short;
using u32 = unsigned int;

typedef __attribute__((ext_vector_type(8))) short bf16x8;   // 8 bf16 (4 VGPRs) MFMA frag
typedef __attribute__((ext_vector_type(4))) float f32x4;
typedef __attribute__((ext_vector_type(8))) u16 u16x8;
typedef __attribute__((ext_vector_type(4))) u16 u16x4;

constexpr int NB = 64, NC = 729, NS = 243, ND = 512, ND2 = 1024;
constexpr int MS = NB * NS;   // 15552 set rows
constexpr int MC = NB * NC;   // 46656 cand rows

__device__ __forceinline__ u16 f2bf(float f) {
  u32 u = __builtin_bit_cast(u32, f);
  return (u16)((u + 0x7fffu + ((u >> 16) & 1u)) >> 16);   // RNE
}
__device__ __forceinline__ float bf2f(u16 h) {
  return __builtin_bit_cast(float, (u32)h << 16);
}
__device__ __forceinline__ void gload16(const void* g, void* l) {
  __builtin_amdgcn_global_load_lds((const __attribute__((address_space(1))) u32*)g,
                                   (__attribute__((address_space(3))) u32*)l, 16, 0, 0);
}

// ---------------- all-weights f32 -> bf16 cast (single launch) ----------------
// ranges (f32x4 units): W_vc 65536 | W_vs 65536 | W1 131072 | W2 131072
__global__ __launch_bounds__(256) void cast_all_k(const float* __restrict__ s0,
                                                  const float* __restrict__ s1,
                                                  const float* __restrict__ s2,
                                                  const float* __restrict__ s3,
                                                  u16* __restrict__ d0, u16* __restrict__ d1,
                                                  u16* __restrict__ d2, u16* __restrict__ d3) {
  int i = blockIdx.x * 256 + threadIdx.x;
  const float* s; u16* d; int off;
  if (i < 65536)       { s = s0; d = d0; off = i; }
  else if (i < 131072) { s = s1; d = d1; off = i - 65536; }
  else if (i < 262144) { s = s2; d = d2; off = i - 131072; }
  else                 { s = s3; d = d3; off = i - 262144; }
  f32x4 v = ((const f32x4*)s)[off];
  u16x4 o;
  o.x = f2bf(v.x); o.y = f2bf(v.y); o.z = f2bf(v.z); o.w = f2bf(v.w);
  ((u16x4*)d)[off] = o;
}

// ---------------- CSR build: register-only ranks (no LDS latency chains) ----------------
__global__ __launch_bounds__(1024) void build_csr_k(const int* __restrict__ idx,
                                                    int* __restrict__ offs,
                                                    int* __restrict__ list) {
  constexpr int NE = 3 * NC;              // 2187 entries
  constexpr int NCH = (NE + 63) / 64;     // 35 chunks
  __shared__ int sidx[NE];
  __shared__ int lrank[NE];
  __shared__ int hist[NCH][NS];
  __shared__ int scan[256];
  __shared__ int soffs[NS];
  const int t = threadIdx.x;
  const int wv = t >> 6, ln = t & 63;

  for (int e = t; e < NE; e += 1024) sidx[e] = idx[e];
  for (int i = t; i < NCH * NS; i += 1024) (&hist[0][0])[i] = 0;
  __syncthreads();

  for (int c = wv; c < NCH; c += 16) {
    int e = c * 64 + ln;
    int s = (e < NE) ? sidx[e] : -1;
    int rank = 0, tot = 0;
#pragma unroll
    for (int l2 = 0; l2 < 64; ++l2) {
      int v = __shfl(s, l2);
      bool m = (v == s) && (s >= 0);
      rank += (m && (l2 < ln)) ? 1 : 0;
      tot  += m ? 1 : 0;
    }
    if (e < NE) {
      lrank[e] = rank;
      if (rank == 0) hist[c][s] = tot;
    }
  }
  __syncthreads();

  int mycnt = 0;
  if (t < NS) {
    int run = 0;
#pragma unroll 5
    for (int c = 0; c < NCH; ++c) { int v = hist[c][t]; hist[c][t] = run; run += v; }
    mycnt = run;
  }
  if (t < 256) scan[t] = (t < NS) ? mycnt : 0;
  __syncthreads();

  for (int d = 1; d < 256; d <<= 1) {
    int v = 0;
    if (t < 256 && t >= d) v = scan[t - d];
    __syncthreads();
    if (t < 256) scan[t] += v;
    __syncthreads();
  }
  if (t < NS) {
    soffs[t] = scan[t] - mycnt;
    offs[t] = scan[t] - mycnt;
  }
  if (t == 0) offs[NS] = NE;
  __syncthreads();

  for (int e = t; e < NE; e += 1024) {
    int s = sidx[e];
    list[soffs[s] + hist[e >> 6][s] + lrank[e]] = e / 3;
  }
}

// ---------------- per-set aggregation of cand_feat (pre-GEMM1 scatter) ----------------
__global__ __launch_bounds__(256) void agg_k(const float* __restrict__ cand_feat,
                                             const int* __restrict__ offs,
                                             const int* __restrict__ list,
                                             u16* __restrict__ agg) {
  int row = blockIdx.x * 4 + (threadIdx.x >> 6);
  if (row >= MS) return;
  int lane = threadIdx.x & 63;
  int b = row / NS, s = row - b * NS;
  int e0 = offs[s], e1 = offs[s + 1];
  const float* base = cand_feat + (size_t)b * NC * ND + lane * 8;
  f32x4 a0 = {0.f, 0.f, 0.f, 0.f}, a1 = {0.f, 0.f, 0.f, 0.f};
  for (int e = e0; e < e1; ++e) {
    const float* p = base + (size_t)list[e] * ND;
    a0 += *(const f32x4*)p;
    a1 += *(const f32x4*)(p + 4);
  }
  u16x8 o;
  o[0] = f2bf(a0.x); o[1] = f2bf(a0.y); o[2] = f2bf(a0.z); o[3] = f2bf(a0.w);
  o[4] = f2bf(a1.x); o[5] = f2bf(a1.y); o[6] = f2bf(a1.z); o[7] = f2bf(a1.w);
  *(u16x8*)(agg + (size_t)row * ND + lane * 8) = o;
}

// ============ 128x128 bf16 GEMM v4, C = A @ B^T ============
// BK=64 (128B rows = 8 x 16B slots), full 3-bit XOR swizzle slot = chunk ^ (row&7):
// pre-swizzled global src, linear global_load_lds dest, swizzled ds_read_b128
// (R7-verified: SQ_LDS_BANK_CONFLICT = 0). Single-buffer 32KB LDS, 4 blocks/CU.
// Supertile order (mt=wg/NT) + general bijective XCD swizzle (m204).
// EP=0: f32 no bias. EP=1: bias+relu->bf16. EP=2: bias->bf16. EP=3: no bias->bf16.
template <int EP>
__global__ __launch_bounds__(256, 4) void gemm_k64(const u16* __restrict__ A,
                                                   const u16* __restrict__ Bw,
                                                   void* __restrict__ Out,
                                                   const float* __restrict__ bias,
                                                   int M, int N, int K) {
  constexpr int BK = 64;
  __shared__ u16 lA[128 * BK];   // 16 KB
  __shared__ u16 lB[128 * BK];   // 16 KB
  const int t = threadIdx.x, wid = t >> 6, lane = t & 63;
  const int NT = N >> 7;
  const int nwg = gridDim.x;
  int wg;
  { int q = nwg >> 3, r = nwg & 7, x = blockIdx.x & 7, p = blockIdx.x >> 3;
    wg = (x < r ? x * (q + 1) : r * (q + 1) + (x - r) * q) + p; }   // bijective
  const int mt = wg / NT, nt = wg % NT;
  const int m0 = mt << 7, n0 = nt << 7;

  // staging: 4 issues each for A,B; chunk-slot s = i*256+t; row=s>>3, slot=s&7
  const u16* gA[4]; const u16* gB[4]; int ldo[4];
#pragma unroll
  for (int i = 0; i < 4; ++i) {
    int s = i * 256 + t;
    int r = s >> 3, j = s & 7;
    int cj = (j ^ (r & 7)) * 8;              // pre-swizzled source chunk (elements)
    int ar = m0 + r; if (ar > M - 1) ar = M - 1;   // tail clamp (A only)
    gA[i] = A + (size_t)ar * K + cj;
    gB[i] = Bw + (size_t)(n0 + r) * K + cj;
    ldo[i] = s * 8;                          // linear LDS dest (elements)
  }

  const int li = lane & 15, g0 = lane >> 4;
  const int wr = wid >> 1, wc = wid & 1;
  int aOff[4], bOff[4];
#pragma unroll
  for (int i = 0; i < 4; ++i) {
    int rowA = wr * 64 + i * 16 + li;
    int rowB = wc * 64 + i * 16 + li;
    aOff[i] = rowA * 64 + ((g0 ^ (li & 7)) << 3);
    bOff[i] = rowB * 64 + ((g0 ^ (li & 7)) << 3);
  }

  f32x4 acc[4][4] = {};

  for (int kt = 0; kt < K; kt += BK) {
#pragma unroll
    for (int i = 0; i < 4; ++i) gload16(gA[i], lA + ldo[i]);
#pragma unroll
    for (int i = 0; i < 4; ++i) gload16(gB[i], lB + ldo[i]);
#pragma unroll
    for (int i = 0; i < 4; ++i) { gA[i] += BK; gB[i] += BK; }
    __syncthreads();
#pragma unroll
    for (int kk = 0; kk < 2; ++kk) {
      bf16x8 af[4], bfr[4];
#pragma unroll
      for (int i = 0; i < 4; ++i) {
        af[i]  = *(const bf16x8*)(lA + (aOff[i] ^ (kk << 5)));
        bfr[i] = *(const bf16x8*)(lB + (bOff[i] ^ (kk << 5)));
      }
#pragma unroll
      for (int mi = 0; mi < 4; ++mi)
#pragma unroll
        for (int ni = 0; ni < 4; ++ni)
          acc[mi][ni] = __builtin_amdgcn_mfma_f32_16x16x32_bf16(af[mi], bfr[ni], acc[mi][ni], 0, 0, 0);
    }
    __syncthreads();
  }

  const int rb = m0 + wr * 64 + (g0 << 2);
  const int cb = n0 + wc * 64 + li;
  if (EP == 0) {
    float* O = (float*)Out;
#pragma unroll
    for (int mi = 0; mi < 4; ++mi)
#pragma unroll
      for (int ni = 0; ni < 4; ++ni) {
        int cc = cb + ni * 16;
#pragma unroll
        for (int r = 0; r < 4; ++r) {
          int rr = rb + mi * 16 + r;
          if (rr < M) O[(size_t)rr * N + cc] = acc[mi][ni][r];
        }
      }
  } else {
    u16* O = (u16*)Out;
    float bv[4];
#pragma unroll
    for (int ni = 0; ni < 4; ++ni) bv[ni] = (EP == 3) ? 0.0f : bias[cb + ni * 16];
#pragma unroll
    for (int mi = 0; mi < 4; ++mi)
#pragma unroll
      for (int ni = 0; ni < 4; ++ni) {
        int cc = cb + ni * 16;
#pragma unroll
        for (int r = 0; r < 4; ++r) {
          int rr = rb + mi * 16 + r;
          float v = acc[mi][ni][r] + bv[ni];
          if (EP == 1) v = fmaxf(v, 0.0f);
          if (rr < M) O[(size_t)rr * N + cc] = f2bf(v);
        }
      }
  }
}

// ---------------- set LN: set_out = LN(set_feat + (u1 + cnt*b_vc)/9) ----------------
__global__ __launch_bounds__(256) void set_ln_k(const u16* __restrict__ u1,
                                                const float* __restrict__ set_feat,
                                                const int* __restrict__ offs,
                                                const float* __restrict__ b_vc,
                                                const float* __restrict__ gam,
                                                const float* __restrict__ bet,
                                                float* __restrict__ set_out,
                                                u16* __restrict__ set_out_bf) {
  int row = blockIdx.x * 4 + (threadIdx.x >> 6);
  if (row >= MS) return;
  int lane = threadIdx.x & 63;
  int s = row % NS;
  float c9 = (float)(offs[s + 1] - offs[s]) * (1.0f / 9.0f);
  size_t base = (size_t)row * ND + lane * 8;
  u16x8 ua = *(const u16x8*)(u1 + base);
  f32x4 s0 = *(const f32x4*)(set_feat + base), s1  = *(const f32x4*)(set_feat + base + 4);
  f32x4 b0 = *(const f32x4*)(b_vc + lane * 8), b1  = *(const f32x4*)(b_vc + lane * 8 + 4);
  f32x4 x0, x1;
#pragma unroll
  for (int i = 0; i < 4; ++i) {
    x0[i] = s0[i] + bf2f(ua[i]) * (1.0f / 9.0f) + b0[i] * c9;
    x1[i] = s1[i] + bf2f(ua[i + 4]) * (1.0f / 9.0f) + b1[i] * c9;
  }
  float sm = 0.f, sq = 0.f;
#pragma unroll
  for (int i = 0; i < 4; ++i) { sm += x0[i] + x1[i]; sq += x0[i] * x0[i] + x1[i] * x1[i]; }
#pragma unroll
  for (int m = 32; m; m >>= 1) { sm += __shfl_xor(sm, m); sq += __shfl_xor(sq, m); }
  float mu = sm * (1.0f / ND);
  float rs = rsqrtf(sq * (1.0f / ND) - mu * mu + 1e-5f);
  f32x4 g0 = *(const f32x4*)(gam + lane * 8), g1 = *(const f32x4*)(gam + lane * 8 + 4);
  f32x4 e0 = *(const f32x4*)(bet + lane * 8), e1 = *(const f32x4*)(bet + lane * 8 + 4);
  f32x4 y0, y1; u16x8 ob;
#pragma unroll
  for (int i = 0; i < 4; ++i) {
    y0[i] = (x0[i] - mu) * rs * g0[i] + e0[i];
    y1[i] = (x1[i] - mu) * rs * g1[i] + e1[i];
    ob[i] = f2bf(y0[i]); ob[i + 4] = f2bf(y1[i]);
  }
  *(f32x4*)(set_out + base) = y0;
  *(f32x4*)(set_out + base + 4) = y1;
  *(u16x8*)(set_out_bf + base) = ob;
}

// ---------------- cand LN: cand_h = LN(cand_feat + mean3(proj) + b_vs) ----------------
__global__ __launch_bounds__(256) void cand_ln_k(const float* __restrict__ cand_feat,
                                                 const u16* __restrict__ proj,
                                                 const int* __restrict__ cidx,
                                                 const float* __restrict__ b_vs,
                                                 const float* __restrict__ gam,
                                                 const float* __restrict__ bet,
                                                 u16* __restrict__ cand_h) {
  int row = blockIdx.x * 4 + (threadIdx.x >> 6);
  if (row >= MC) return;
  int lane = threadIdx.x & 63;
  int b = row / NC, c = row - b * NC;
  int i0 = cidx[c * 3], i1 = cidx[c * 3 + 1], i2 = cidx[c * 3 + 2];
  const u16* pb = proj + (size_t)b * NS * ND + lane * 8;
  u16x8 p0 = *(const u16x8*)(pb + (size_t)i0 * ND);
  u16x8 p1 = *(const u16x8*)(pb + (size_t)i1 * ND);
  u16x8 p2 = *(const u16x8*)(pb + (size_t)i2 * ND);
  size_t base = (size_t)row * ND + lane * 8;
  f32x4 c0 = *(const f32x4*)(cand_feat + base), c1 = *(const f32x4*)(cand_feat + base + 4);
  f32x4 v0 = *(const f32x4*)(b_vs + lane * 8),  v1 = *(const f32x4*)(b_vs + lane * 8 + 4);
  const float third = 1.0f / 3.0f;
  f32x4 x0, x1;
#pragma unroll
  for (int i = 0; i < 4; ++i) {
    x0[i] = c0[i] + (bf2f(p0[i]) + bf2f(p1[i]) + bf2f(p2[i])) * third + v0[i];
    x1[i] = c1[i] + (bf2f(p0[i + 4]) + bf2f(p1[i + 4]) + bf2f(p2[i + 4])) * third + v1[i];
  }
  float sm = 0.f, sq = 0.f;
#pragma unroll
  for (int i = 0; i < 4; ++i) { sm += x0[i] + x1[i]; sq += x0[i] * x0[i] + x1[i] * x1[i]; }
#pragma unroll
  for (int m = 32; m; m >>= 1) { sm += __shfl_xor(sm, m); sq += __shfl_xor(sq, m); }
  float mu = sm * (1.0f / ND);
  float rs = rsqrtf(sq * (1.0f / ND) - mu * mu + 1e-5f);
  f32x4 g0 = *(const f32x4*)(gam + lane * 8), g1 = *(const f32x4*)(gam + lane * 8 + 4);
  f32x4 e0 = *(const f32x4*)(bet + lane * 8), e1 = *(const f32x4*)(bet + lane * 8 + 4);
  u16x8 ob;
#pragma unroll
  for (int i = 0; i < 4; ++i) {
    ob[i]     = f2bf((x0[i] - mu) * rs * g0[i] + e0[i]);
    ob[i + 4] = f2bf((x1[i] - mu) * rs * g1[i] + e1[i]);
  }
  *(u16x8*)(cand_h + base) = ob;
}

// ---------------- final LN: out = LN(cand_h + h2b) (bias folded into h2b) ----------------
__global__ __launch_bounds__(256) void ln_ff_k(const u16* __restrict__ h2b,
                                               const u16* __restrict__ resid,
                                               const float* __restrict__ gam,
                                               const float* __restrict__ bet,
                                               float* __restrict__ out, int nrows) {
  int row = blockIdx.x * 4 + (threadIdx.x >> 6);
  if (row >= nrows) return;
  int lane = threadIdx.x & 63;
  size_t base = (size_t)row * ND + lane * 8;
  u16x8 ha = *(const u16x8*)(h2b + base);
  u16x8 ra = *(const u16x8*)(resid + base);
  float x[8];
  float sm = 0.f, sq = 0.f;
#pragma unroll
  for (int i = 0; i < 8; ++i) {
    x[i] = bf2f(ha[i]) + bf2f(ra[i]);
    sm += x[i]; sq += x[i] * x[i];
  }
#pragma unroll
  for (int m = 32; m; m >>= 1) { sm += __shfl_xor(sm, m); sq += __shfl_xor(sq, m); }
  float mu = sm * (1.0f / ND);
  float rs = rsqrtf(sq * (1.0f / ND) - mu * mu + 1e-5f);
  f32x4 g0 = *(const f32x4*)(gam + lane * 8), g1 = *(const f32x4*)(gam + lane * 8 + 4);
  f32x4 e0 = *(const f32x4*)(bet + lane * 8), e1 = *(const f32x4*)(bet + lane * 8 + 4);
  f32x4 y0, y1;
#pragma unroll
  for (int i = 0; i < 4; ++i) {
    y0[i] = (x[i] - mu) * rs * g0[i] + e0[i];
    y1[i] = (x[i + 4] - mu) * rs * g1[i] + e1[i];
  }
  *(f32x4*)(out + base) = y0;
  *(f32x4*)(out + base + 4) = y1;
}

// ---------------- launcher ----------------
extern "C" void kernel_launch(void* const* d_in, const int* in_sizes, int n_in,
                              void* d_out, int out_size, void* d_ws, size_t ws_size,
                              hipStream_t stream) {
  const float* cand_feat = (const float*)d_in[0];
  const float* set_feat  = (const float*)d_in[1];
  const float* W_vc  = (const float*)d_in[2];
  const float* b_vc  = (const float*)d_in[3];
  const float* W_vs  = (const float*)d_in[4];
  const float* b_vs  = (const float*)d_in[5];
  const float* ff_W1 = (const float*)d_in[6];
  const float* ff_b1 = (const float*)d_in[7];
  const float* ff_W2 = (const float*)d_in[8];
  const float* ff_b2 = (const float*)d_in[9];
  const float* g_set  = (const float*)d_in[10];
  const float* be_set = (const float*)d_in[11];
  const float* g_cand = (const float*)d_in[12];
  const float* be_cand= (const float*)d_in[13];
  const float* g_ff   = (const float*)d_in[14];
  const float* be_ff  = (const float*)d_in[15];
  const int*   cidx   = (const int*)d_in[16];
  (void)in_sizes; (void)n_in; (void)out_size; (void)ws_size;

  // workspace layout (ws_size ~= 509MB per harness poison; watermark here ~116MB)
  char* ws = (char*)d_ws;
  u16* w_vc_b = (u16*)(ws + 0);
  u16* w_vs_b = (u16*)(ws + (512 << 10));
  u16* w1_b   = (u16*)(ws + (1 << 20));
  u16* w2_b   = (u16*)(ws + (2 << 20));
  int* offs   = (int*)(ws + (3 << 20));
  int* list   = (int*)(ws + (3 << 20) + 4096);
  u16* setb   = (u16*)(ws + (4 << 20));            // 15.9 MB  set_out bf16
  u16* candh  = (u16*)(ws + (20 << 20));           // 47.8 MB  cand_h bf16
  u16* h2b    = (u16*)(ws + (size_t)(68 << 20));   // 47.8 MB  FF2 out bf16

  // d_out region reuse (cand region = 95.55 MB, written last):
  float* out_cand = (float*)d_out;
  float* out_set  = out_cand + (size_t)MC * ND;
  u16*   agg  = (u16*)out_set;     // dead before set_out written
  u16*   u1   = (u16*)out_cand;    // GEMM1 out (bf16), dead after set_ln
  u16*   proj = (u16*)out_cand;    // GEMM2 out (bf16), dead after cand_ln
  u16*   h1   = (u16*)out_cand;    // FF1 out (46656 x 1024 bf16 = exactly the cand region)

  cast_all_k<<<1536, 256, 0, stream>>>(W_vc, W_vs, ff_W1, ff_W2, w_vc_b, w_vs_b, w1_b, w2_b);
  build_csr_k<<<1, 1024, 0, stream>>>(cidx, offs, list);
  agg_k<<<(MS + 3) / 4, 256, 0, stream>>>(cand_feat, offs, list, agg);
  gemm_k64<3><<<122 * 4, 256, 0, stream>>>(agg, w_vc_b, u1, nullptr, MS, ND, ND);
  set_ln_k<<<(MS + 3) / 4, 256, 0, stream>>>(u1, set_feat, offs, b_vc, g_set, be_set, out_set, setb);
  gemm_k64<3><<<122 * 4, 256, 0, stream>>>(setb, w_vs_b, proj, nullptr, MS, ND, ND);
  cand_ln_k<<<(MC + 3) / 4, 256, 0, stream>>>(cand_feat, proj, cidx, b_vs, g_cand, be_cand, candh);
  gemm_k64<1><<<365 * 8, 256, 0, stream>>>(candh, w1_b, h1, ff_b1, MC, ND2, ND);
  gemm_k64<2><<<365 * 4, 256, 0, stream>>>(h1, w2_b, h2b, ff_b2, MC, ND, ND2);
  ln_ff_k<<<(MC + 3) / 4, 256, 0, stream>>>(h2b, candh, g_ff, be_ff, out_cand, MC);
}